// Round 12
// baseline (61.225 us; speedup 1.0000x reference)
//
#include <hip/hip_runtime.h>

// SHToGridDensity: density[row][g] = sum_{lm,r} coeffs[row][lm][r]*Y[lm][g]*R[r][g]
// row in 0..255, g in 0..35936. Inputs f32; OUTPUT f32 (r9-verified).
//
// GEMM D[256][G] = A[256][K=400] x B[400][G] on mfma_f32_32x32x16_bf16.
// K = 25 lm-steps x 16 r: each 32x32x16 MFMA consumes exactly one lm (no pad).
// Per-lane operand map (BOTH operands, shared bijection — r9-verified pattern):
//   A: row = l&31 (+32*mt), elem j at k-local = (l>>5)*8 + j  (r = that)
//   B: col = l&31, same k-local map, generated in-register:
//      elem j = Y[lm][g] * R[(l>>5)*8+j][g], RNE via v_cvt_pk_bf16_f32
// D: col = l&31, row = (reg&3) + 8*(reg>>2) + 4*(l>>5)   [m74/m101 HW-verified]
//
// Structure: block = 128 threads = 2 waves; wave owns 1 n-tile (32 cols) x all
// 8 m-tiles (acc 128 VGPR). Per k-step: 8 loads + 8 MFMAs -> 2x FLOP/load of
// r10 (r11 post-mortem: ratio, not traffic, was the regression cause).
// grid = ceil(35937/64) = 562.

#define G_TOTAL 35937
#define N_ROWS  256

typedef __attribute__((ext_vector_type(8))) short bf16x8;
typedef __attribute__((ext_vector_type(16))) float f32x16;

__device__ __forceinline__ unsigned short f32_bf16_rne(float f) {
    unsigned u = __float_as_uint(f);
    u += 0x7FFFu + ((u >> 16) & 1u);
    return (unsigned short)(u >> 16);
}

__constant__ int c_lmFlat[25] = {4, 12,13,14, 20,21,22,23,24,
                                 28,29,30,31,32,33,34,
                                 36,37,38,39,40,41,42,43,44};

// pack: fragment (ks, mt, lane) -> packedA[(ks*8+mt)*64 + lane] (16B/lane).
// element j = coeffs[mt*32 + (lane&31)][lmFlat[ks]][(lane>>5)*8 + j]
// grid exact: 25*8*64 = 12800 threads = 50 blocks.
__global__ void pack_coeffs32(const float* __restrict__ coeffs,
                              unsigned short* __restrict__ packedA) {
    int t = blockIdx.x * 256 + threadIdx.x;
    int lane = t & 63;
    int frag = t >> 6;          // ks*8 + mt
    int mt = frag & 7;
    int ks = frag >> 3;         // 0..24
    int row = mt * 32 + (lane & 31);
    int base = row * 720 + c_lmFlat[ks] * 16 + (lane >> 5) * 8;
    unsigned w[4];
#pragma unroll
    for (int p = 0; p < 4; ++p) {
        unsigned short lo = f32_bf16_rne(coeffs[base + 2 * p]);
        unsigned short hi = f32_bf16_rne(coeffs[base + 2 * p + 1]);
        w[p] = (unsigned)lo | ((unsigned)hi << 16);
    }
    ((uint4*)packedA)[t] = make_uint4(w[0], w[1], w[2], w[3]);
}

__global__ __launch_bounds__(128, 2) void sh_density32(
        const unsigned short* __restrict__ packedA,
        const float* __restrict__ Y,
        const float* __restrict__ Rb,
        float* __restrict__ out) {
    const int tx = threadIdx.x;
    const int l  = tx & 63;
    const int w  = tx >> 6;          // 0..1 (n-tile within block)
    const int cl = l & 31;
    const int kg = l >> 5;           // 0..1 (k-group)

    const int g  = blockIdx.x * 64 + w * 32 + cl;
    const int gc = g < G_TOTAL ? g : G_TOTAL - 1;

    constexpr int lmFlat[25] = {4, 12,13,14, 20,21,22,23,24,
                                28,29,30,31,32,33,34,
                                36,37,38,39,40,41,42,43,44};

    float YA[25];
#pragma unroll
    for (int i = 0; i < 25; ++i) YA[i] = Y[lmFlat[i] * G_TOTAL + gc];

    float RA[8];
#pragma unroll
    for (int j = 0; j < 8; ++j) RA[j] = Rb[(kg * 8 + j) * G_TOTAL + gc];

    f32x16 acc[8];
#pragma unroll
    for (int i = 0; i < 8; ++i)
#pragma unroll
        for (int q = 0; q < 16; ++q) acc[i][q] = 0.0f;

    const bf16x8* __restrict__ Ap = (const bf16x8*)packedA;

#pragma unroll
    for (int ks = 0; ks < 25; ++ks) {
        const float y = YA[ks];
        union { unsigned int u[4]; bf16x8 v; } fb;
#pragma unroll
        for (int p = 0; p < 4; ++p) {
            float lo = y * RA[2 * p];
            float hi = y * RA[2 * p + 1];
            unsigned r;
            asm("v_cvt_pk_bf16_f32 %0, %1, %2" : "=v"(r) : "v"(lo), "v"(hi));
            fb.u[p] = r;   // elem 2p in [15:0], 2p+1 in [31:16] == pack order
        }
#pragma unroll
        for (int mt = 0; mt < 8; ++mt) {
            bf16x8 a = Ap[(ks * 8 + mt) * 64 + l];
            acc[mt] = __builtin_amdgcn_mfma_f32_32x32x16_bf16(a, fb.v, acc[mt], 0, 0, 0);
        }
    }

    if (g < G_TOTAL) {
#pragma unroll
        for (int mt = 0; mt < 8; ++mt) {
#pragma unroll
            for (int reg = 0; reg < 16; ++reg) {
                int row = mt * 32 + (reg & 3) + 8 * (reg >> 2) + 4 * kg;
                out[row * G_TOTAL + g] = acc[mt][reg];
            }
        }
    }
}

extern "C" void kernel_launch(void* const* d_in, const int* in_sizes, int n_in,
                              void* d_out, int out_size, void* d_ws, size_t ws_size,
                              hipStream_t stream) {
    // pointer identification by element count (robust to dict-order changes)
    const float *pC = nullptr, *pY = nullptr, *pR = nullptr;
    if (n_in >= 3) {
        for (int i = 0; i < 3; ++i) {
            if      (in_sizes[i] == 256 * 720)    pC = (const float*)d_in[i];
            else if (in_sizes[i] == 45 * G_TOTAL) pY = (const float*)d_in[i];
            else if (in_sizes[i] == 16 * G_TOTAL) pR = (const float*)d_in[i];
        }
    }
    if (!pC || !pY || !pR) {
        pC = (const float*)d_in[0];
        pY = (const float*)d_in[1];
        pR = (const float*)d_in[2];
    }

    float* out = (float*)d_out;                       // f32 output (r9-verified)
    unsigned short* packedA = (unsigned short*)d_ws;  // 204800 B

    pack_coeffs32<<<50, 256, 0, stream>>>(pC, packedA);
    sh_density32<<<562, 128, 0, stream>>>(packedA, pY, pR, out);

    (void)out_size; (void)n_in; (void)ws_size;
}

// Round 13
// 33.872 us; speedup vs baseline: 1.8075x; 1.8075x over previous
//
#include <hip/hip_runtime.h>

// SHToGridDensity: density[row][g] = sum_{lm,r} coeffs[row][lm][r]*Y[lm][g]*R[r][g]
// row in 0..255, g in 0..35936. Inputs f32; OUTPUT f32 (r9-verified).
//
// GEMM D[256][G] = A[256][K=400] x B[400][G] on mfma_f32_32x32x16_bf16.
// K = 25 lm-steps x 16 r: each MFMA consumes exactly one lm (no pad).
// Per-lane operand map (BOTH operands, shared bijection — r12 on-device
// verified, absmax 0.125):
//   A: row = l&31 (+32*mt), elem j at k-local = (l>>5)*8 + j
//   B: col = l&31, same k-local map, in-register:
//      elem j = Y[lm][g] * R[(l>>5)*8+j][g], RNE via v_cvt_pk_bf16_f32
// D: col = l&31, row = (reg&3) + 8*(reg>>2) + 4*(l>>5)  [m74/m101 HW-verified]
//
// r13 restructure (r12 post-mortem: 1124 waves = 1.1/SIMD, Occupancy 10%,
// all pipes <11% -> latency-bound): wave = 32 cols x 2 m-tiles. Block = 4
// waves = 1 col-slab x 256 rows; grid = 1124 -> 4496 waves (4.4/SIMD, full
// 4-block/CU residency). Math bit-identical to r12.

#define G_TOTAL 35937
#define N_ROWS  256

typedef __attribute__((ext_vector_type(8))) short bf16x8;
typedef __attribute__((ext_vector_type(16))) float f32x16;

__device__ __forceinline__ unsigned short f32_bf16_rne(float f) {
    unsigned u = __float_as_uint(f);
    u += 0x7FFFu + ((u >> 16) & 1u);
    return (unsigned short)(u >> 16);
}

__constant__ int c_lmFlat[25] = {4, 12,13,14, 20,21,22,23,24,
                                 28,29,30,31,32,33,34,
                                 36,37,38,39,40,41,42,43,44};

// pack: fragment (ks, mt, lane) -> packedA[(ks*8+mt)*64 + lane] (16B/lane).
// element j = coeffs[mt*32 + (lane&31)][lmFlat[ks]][(lane>>5)*8 + j]
// grid exact: 25*8*64 = 12800 threads = 50 blocks.  (r12-verified)
__global__ void pack_coeffs32(const float* __restrict__ coeffs,
                              unsigned short* __restrict__ packedA) {
    int t = blockIdx.x * 256 + threadIdx.x;
    int lane = t & 63;
    int frag = t >> 6;          // ks*8 + mt
    int mt = frag & 7;
    int ks = frag >> 3;         // 0..24
    int row = mt * 32 + (lane & 31);
    int base = row * 720 + c_lmFlat[ks] * 16 + (lane >> 5) * 8;
    unsigned w[4];
#pragma unroll
    for (int p = 0; p < 4; ++p) {
        unsigned short lo = f32_bf16_rne(coeffs[base + 2 * p]);
        unsigned short hi = f32_bf16_rne(coeffs[base + 2 * p + 1]);
        w[p] = (unsigned)lo | ((unsigned)hi << 16);
    }
    ((uint4*)packedA)[t] = make_uint4(w[0], w[1], w[2], w[3]);
}

// Main GEMM. Block = 256 threads = 4 waves; wave w owns m-tiles {2w, 2w+1}
// for the block's 32-col slab. grid = ceil(35937/32) = 1124.
__global__ __launch_bounds__(256, 4) void sh_density32(
        const unsigned short* __restrict__ packedA,
        const float* __restrict__ Y,
        const float* __restrict__ Rb,
        float* __restrict__ out) {
    const int tx = threadIdx.x;
    const int l  = tx & 63;
    const int w  = tx >> 6;          // wave 0..3 -> m-tiles {2w, 2w+1}
    const int cl = l & 31;
    const int kg = l >> 5;           // 0..1 (k-group)

    const int g  = blockIdx.x * 32 + cl;
    const int gc = g < G_TOTAL ? g : G_TOTAL - 1;

    constexpr int lmFlat[25] = {4, 12,13,14, 20,21,22,23,24,
                                28,29,30,31,32,33,34,
                                36,37,38,39,40,41,42,43,44};

    float YA[25];
#pragma unroll
    for (int i = 0; i < 25; ++i) YA[i] = Y[lmFlat[i] * G_TOTAL + gc];

    float RA[8];
#pragma unroll
    for (int j = 0; j < 8; ++j) RA[j] = Rb[(kg * 8 + j) * G_TOTAL + gc];

    f32x16 acc0, acc1;
#pragma unroll
    for (int q = 0; q < 16; ++q) { acc0[q] = 0.0f; acc1[q] = 0.0f; }

    const bf16x8* __restrict__ Ap = (const bf16x8*)packedA;

#pragma unroll
    for (int ks = 0; ks < 25; ++ks) {
        const float y = YA[ks];
        union { unsigned int u[4]; bf16x8 v; } fb;
#pragma unroll
        for (int p = 0; p < 4; ++p) {
            float lo = y * RA[2 * p];
            float hi = y * RA[2 * p + 1];
            unsigned r;
            asm("v_cvt_pk_bf16_f32 %0, %1, %2" : "=v"(r) : "v"(lo), "v"(hi));
            fb.u[p] = r;   // elem 2p in [15:0], 2p+1 in [31:16] == pack order
        }
        bf16x8 a0 = Ap[(ks * 8 + 2 * w)     * 64 + l];
        bf16x8 a1 = Ap[(ks * 8 + 2 * w + 1) * 64 + l];
        acc0 = __builtin_amdgcn_mfma_f32_32x32x16_bf16(a0, fb.v, acc0, 0, 0, 0);
        acc1 = __builtin_amdgcn_mfma_f32_32x32x16_bf16(a1, fb.v, acc1, 0, 0, 0);
    }

    if (g < G_TOTAL) {
        const int rb0 = (2 * w)     * 32 + 4 * kg;
        const int rb1 = (2 * w + 1) * 32 + 4 * kg;
#pragma unroll
        for (int reg = 0; reg < 16; ++reg) {
            int ro = (reg & 3) + 8 * (reg >> 2);
            out[(rb0 + ro) * G_TOTAL + g] = acc0[reg];
            out[(rb1 + ro) * G_TOTAL + g] = acc1[reg];
        }
    }
}

extern "C" void kernel_launch(void* const* d_in, const int* in_sizes, int n_in,
                              void* d_out, int out_size, void* d_ws, size_t ws_size,
                              hipStream_t stream) {
    // pointer identification by element count (robust to dict-order changes)
    const float *pC = nullptr, *pY = nullptr, *pR = nullptr;
    if (n_in >= 3) {
        for (int i = 0; i < 3; ++i) {
            if      (in_sizes[i] == 256 * 720)    pC = (const float*)d_in[i];
            else if (in_sizes[i] == 45 * G_TOTAL) pY = (const float*)d_in[i];
            else if (in_sizes[i] == 16 * G_TOTAL) pR = (const float*)d_in[i];
        }
    }
    if (!pC || !pY || !pR) {
        pC = (const float*)d_in[0];
        pY = (const float*)d_in[1];
        pR = (const float*)d_in[2];
    }

    float* out = (float*)d_out;                       // f32 output (r9-verified)
    unsigned short* packedA = (unsigned short*)d_ws;  // 204800 B

    pack_coeffs32<<<50, 256, 0, stream>>>(pC, packedA);
    sh_density32<<<1124, 256, 0, stream>>>(packedA, pY, pR, out);

    (void)out_size; (void)n_in; (void)ws_size;
}

// Round 14
// 27.668 us; speedup vs baseline: 2.2128x; 1.2242x over previous
//
#include <hip/hip_runtime.h>

// SHToGridDensity: density[row][g] = sum_{lm,r} coeffs[row][lm][r]*Y[lm][g]*R[r][g]
// row in 0..255, g in 0..35936. Inputs f32; OUTPUT f32 (r9-verified).
//
// GEMM D[256][G] = A[256][K=400] x B[400][G] on mfma_f32_32x32x16_bf16.
// K = 25 lm-steps x 16 r: each MFMA consumes exactly one lm (no pad).
// Per-lane operand map (BOTH operands, shared bijection — r12/r13 on-device
// verified, absmax 0.125):
//   A: row = l&31 (+32*mt), elem j at k-local = (l>>5)*8 + j
//   B: col = l&31, same k-local map, in-register:
//      elem j = Y[lm][g] * R[(l>>5)*8+j][g], RNE via v_cvt_pk_bf16_f32
// D: col = l&31, row = (reg&3) + 8*(reg>>2) + 4*(l>>5)  [m74/m101 HW-verified]
//
// r14 restructure (r13 post-mortem: K-loop = 25x{2 L2-latency loads -> 2 MFMAs}
// with 128-VGPR cap -> latency-bound at ~30us despite 4.4 waves/SIMD):
//   block = 512 thr = 8 waves; blockIdx.y = m-tile PAIR; A for the pair
//   (50 KB) staged ONCE into LDS, K-loop reads ds_read_b128 (conflict-free
//   contiguous). 8 waves = 8 distinct 32-col slabs (no Y/R duplication).
//   grid = 141 x 4 -> 4512 waves = 4.4/SIMD at 2 blocks/CU (LDS 100KB/CU).
// Math bit-identical to r13.

#define G_TOTAL 35937
#define N_ROWS  256

typedef __attribute__((ext_vector_type(8))) short bf16x8;
typedef __attribute__((ext_vector_type(16))) float f32x16;

__device__ __forceinline__ unsigned short f32_bf16_rne(float f) {
    unsigned u = __float_as_uint(f);
    u += 0x7FFFu + ((u >> 16) & 1u);
    return (unsigned short)(u >> 16);
}

__constant__ int c_lmFlat[25] = {4, 12,13,14, 20,21,22,23,24,
                                 28,29,30,31,32,33,34,
                                 36,37,38,39,40,41,42,43,44};

// pack: fragment (ks, mt, lane) -> packedA[(ks*8+mt)*64 + lane] (16B/lane).
// element j = coeffs[mt*32 + (lane&31)][lmFlat[ks]][(lane>>5)*8 + j]
// grid exact: 25*8*64 = 12800 threads = 50 blocks.  (r12-verified)
__global__ void pack_coeffs32(const float* __restrict__ coeffs,
                              unsigned short* __restrict__ packedA) {
    int t = blockIdx.x * 256 + threadIdx.x;
    int lane = t & 63;
    int frag = t >> 6;          // ks*8 + mt
    int mt = frag & 7;
    int ks = frag >> 3;         // 0..24
    int row = mt * 32 + (lane & 31);
    int base = row * 720 + c_lmFlat[ks] * 16 + (lane >> 5) * 8;
    unsigned w[4];
#pragma unroll
    for (int p = 0; p < 4; ++p) {
        unsigned short lo = f32_bf16_rne(coeffs[base + 2 * p]);
        unsigned short hi = f32_bf16_rne(coeffs[base + 2 * p + 1]);
        w[p] = (unsigned)lo | ((unsigned)hi << 16);
    }
    ((uint4*)packedA)[t] = make_uint4(w[0], w[1], w[2], w[3]);
}

// Main GEMM. Block = 512 threads = 8 waves. blockIdx.y -> m-tiles {2y,2y+1}
// (A staged in LDS); wave w -> col-slab blockIdx.x*256 + w*32.
// grid = (ceil(35937/256)=141, 4).
__global__ __launch_bounds__(512, 4) void sh_density32(
        const unsigned short* __restrict__ packedA,
        const float* __restrict__ Y,
        const float* __restrict__ Rb,
        float* __restrict__ out) {
    __shared__ uint4 Alds[50 * 64];            // 51200 B: [ks*2+mtl][lane]
    const int tx = threadIdx.x;
    const int l  = tx & 63;
    const int w  = tx >> 6;          // 0..7 col-slab
    const int cl = l & 31;
    const int kg = l >> 5;           // 0..1 k-group

    const int bY = blockIdx.y;       // m-pair: global m-tiles {2bY, 2bY+1}
    const int g  = blockIdx.x * 256 + w * 32 + cl;
    const int gc = g < G_TOTAL ? g : G_TOTAL - 1;

    // ---- one-shot A stage: 50 fragments (2 m-tiles x 25 ks) -> LDS ----
    const uint4* __restrict__ Ag = (const uint4*)packedA;
#pragma unroll
    for (int i = 0; i < 7; ++i) {              // 7*512 = 3584 >= 3200
        int s = tx + i * 512;
        if (s < 3200) {
            int lane = s & 63;
            int f    = s >> 6;                 // ks*2 + mtl
            int ks   = f >> 1;
            int mtl  = f & 1;
            Alds[s] = Ag[(ks * 8 + 2 * bY + mtl) * 64 + lane];
        }
    }

    // ---- per-lane B-operand state (overlaps with staging) ----
    constexpr int lmFlat[25] = {4, 12,13,14, 20,21,22,23,24,
                                28,29,30,31,32,33,34,
                                36,37,38,39,40,41,42,43,44};
    float YA[25];
#pragma unroll
    for (int i = 0; i < 25; ++i) YA[i] = Y[lmFlat[i] * G_TOTAL + gc];

    float RA[8];
#pragma unroll
    for (int j = 0; j < 8; ++j) RA[j] = Rb[(kg * 8 + j) * G_TOTAL + gc];

    f32x16 acc0, acc1;
#pragma unroll
    for (int q = 0; q < 16; ++q) { acc0[q] = 0.0f; acc1[q] = 0.0f; }

    __syncthreads();

    // ---- K-loop: 25 steps, A from LDS (ds_read_b128, conflict-free) ----
    const bf16x8* __restrict__ Al = (const bf16x8*)Alds;
#pragma unroll
    for (int ks = 0; ks < 25; ++ks) {
        const float y = YA[ks];
        union { unsigned int u[4]; bf16x8 v; } fb;
#pragma unroll
        for (int p = 0; p < 4; ++p) {
            float lo = y * RA[2 * p];
            float hi = y * RA[2 * p + 1];
            unsigned r;
            asm("v_cvt_pk_bf16_f32 %0, %1, %2" : "=v"(r) : "v"(lo), "v"(hi));
            fb.u[p] = r;   // elem 2p in [15:0], 2p+1 in [31:16] == pack order
        }
        bf16x8 a0 = Al[(ks * 2 + 0) * 64 + l];
        bf16x8 a1 = Al[(ks * 2 + 1) * 64 + l];
        acc0 = __builtin_amdgcn_mfma_f32_32x32x16_bf16(a0, fb.v, acc0, 0, 0, 0);
        acc1 = __builtin_amdgcn_mfma_f32_32x32x16_bf16(a1, fb.v, acc1, 0, 0, 0);
    }

    // ---- epilogue ----
    if (g < G_TOTAL) {
        const int rb0 = (2 * bY)     * 32 + 4 * kg;
        const int rb1 = (2 * bY + 1) * 32 + 4 * kg;
#pragma unroll
        for (int reg = 0; reg < 16; ++reg) {
            int ro = (reg & 3) + 8 * (reg >> 2);
            out[(rb0 + ro) * G_TOTAL + g] = acc0[reg];
            out[(rb1 + ro) * G_TOTAL + g] = acc1[reg];
        }
    }
}

extern "C" void kernel_launch(void* const* d_in, const int* in_sizes, int n_in,
                              void* d_out, int out_size, void* d_ws, size_t ws_size,
                              hipStream_t stream) {
    // pointer identification by element count (robust to dict-order changes)
    const float *pC = nullptr, *pY = nullptr, *pR = nullptr;
    if (n_in >= 3) {
        for (int i = 0; i < 3; ++i) {
            if      (in_sizes[i] == 256 * 720)    pC = (const float*)d_in[i];
            else if (in_sizes[i] == 45 * G_TOTAL) pY = (const float*)d_in[i];
            else if (in_sizes[i] == 16 * G_TOTAL) pR = (const float*)d_in[i];
        }
    }
    if (!pC || !pY || !pR) {
        pC = (const float*)d_in[0];
        pY = (const float*)d_in[1];
        pR = (const float*)d_in[2];
    }

    float* out = (float*)d_out;                       // f32 output (r9-verified)
    unsigned short* packedA = (unsigned short*)d_ws;  // 204800 B

    pack_coeffs32<<<50, 256, 0, stream>>>(pC, packedA);
    dim3 grid(141, 4);
    sh_density32<<<grid, 512, 0, stream>>>(packedA, pY, pR, out);

    (void)out_size; (void)n_in; (void)ws_size;
}

// Round 15
// 24.699 us; speedup vs baseline: 2.4788x; 1.1202x over previous
//
#include <hip/hip_runtime.h>

// SHToGridDensity: density[row][g] = sum_{lm,r} coeffs[row][lm][r]*Y[lm][g]*R[r][g]
// row in 0..255, g in 0..35936. Inputs f32; OUTPUT f32 (r9-verified).
//
// GEMM D[256][G] = A[256][K=400] x B[400][G] on mfma_f32_32x32x16_bf16.
// K = 25 lm-steps x 16 r: each MFMA consumes exactly one lm (no pad).
// Per-lane operand map (BOTH operands, shared bijection — r12/r13/r14
// on-device verified, absmax 0.125):
//   A: row = l&31 (+32*mt), elem j at k-local = (l>>5)*8 + j
//   B: col = l&31, same k-local map, in-register:
//      elem j = Y[lm][g] * R[(l>>5)*8+j][g], RNE via v_cvt_pk_bf16_f32
// D: col = l&31, row = (reg&3) + 8*(reg>>2) + 4*(l>>5)  [m74/m101 HW-verified]
//
// r15 (r14 post-mortem: ~10us of the 27.7 is pack dispatch + launch gap +
// phase serialization): SINGLE fused kernel. Each block stages its m-pair's
// A directly from raw f32 coeffs -> cvt_pk RNE bf16 -> LDS (conflict-free
// ds_write_b128), overlapped with Y/R loads. K-loop bit-identical to r14.

#define G_TOTAL 35937
#define N_ROWS  256

typedef __attribute__((ext_vector_type(8))) short bf16x8;
typedef __attribute__((ext_vector_type(16))) float f32x16;

__constant__ int c_lmFlat[25] = {4, 12,13,14, 20,21,22,23,24,
                                 28,29,30,31,32,33,34,
                                 36,37,38,39,40,41,42,43,44};

// Block = 512 threads = 8 waves. blockIdx.y -> m-tiles {2y,2y+1} (A staged
// from coeffs into LDS); wave w -> col-slab blockIdx.x*256 + w*32.
// grid = (ceil(35937/256)=141, 4).
__global__ __launch_bounds__(512, 4) void sh_fused(
        const float* __restrict__ coeffs,
        const float* __restrict__ Y,
        const float* __restrict__ Rb,
        float* __restrict__ out) {
    __shared__ uint4 Alds[50 * 64];            // 51200 B: [ks*2+mtl][lane]
    const int tx = threadIdx.x;
    const int l  = tx & 63;
    const int w  = tx >> 6;          // 0..7 col-slab
    const int cl = l & 31;
    const int kg = l >> 5;           // 0..1 k-group

    const int bY = blockIdx.y;       // m-pair: global m-tiles {2bY, 2bY+1}
    const int g  = blockIdx.x * 256 + w * 32 + cl;
    const int gc = g < G_TOTAL ? g : G_TOTAL - 1;

    // ---- fused A stage: raw coeffs f32 -> RNE bf16 fragments in LDS ----
    // chunk c (0..1599): ks = c>>6, rowl = c&63. 16 f32 at
    // coeffs[(bY*64+rowl)*720 + lmFlat[ks]*16] -> 8 cvt_pk -> 2 ds_write_b128.
    // lanes -> consecutive rowl -> contiguous LDS (conflict-free).
#pragma unroll
    for (int i = 0; i < 4; ++i) {
        int c = tx + i * 512;
        if (c < 1600) {
            int ks   = c >> 6;
            int rowl = c & 63;
            int mtl  = rowl >> 5;
            int r32  = rowl & 31;
            const float4* src = (const float4*)(coeffs + (bY * 64 + rowl) * 720
                                                + c_lmFlat[ks] * 16);
            float4 f0 = src[0], f1 = src[1], f2 = src[2], f3 = src[3];
            unsigned u0, u1, u2, u3, u4, u5, u6, u7;
            asm("v_cvt_pk_bf16_f32 %0, %1, %2" : "=v"(u0) : "v"(f0.x), "v"(f0.y));
            asm("v_cvt_pk_bf16_f32 %0, %1, %2" : "=v"(u1) : "v"(f0.z), "v"(f0.w));
            asm("v_cvt_pk_bf16_f32 %0, %1, %2" : "=v"(u2) : "v"(f1.x), "v"(f1.y));
            asm("v_cvt_pk_bf16_f32 %0, %1, %2" : "=v"(u3) : "v"(f1.z), "v"(f1.w));
            asm("v_cvt_pk_bf16_f32 %0, %1, %2" : "=v"(u4) : "v"(f2.x), "v"(f2.y));
            asm("v_cvt_pk_bf16_f32 %0, %1, %2" : "=v"(u5) : "v"(f2.z), "v"(f2.w));
            asm("v_cvt_pk_bf16_f32 %0, %1, %2" : "=v"(u6) : "v"(f3.x), "v"(f3.y));
            asm("v_cvt_pk_bf16_f32 %0, %1, %2" : "=v"(u7) : "v"(f3.z), "v"(f3.w));
            int fbase = (ks * 2 + mtl) * 64;
            Alds[fbase + r32]      = make_uint4(u0, u1, u2, u3);  // kg=0 lane
            Alds[fbase + 32 + r32] = make_uint4(u4, u5, u6, u7);  // kg=1 lane
        }
    }

    // ---- per-lane B-operand state (overlaps with staging loads) ----
    constexpr int lmFlat[25] = {4, 12,13,14, 20,21,22,23,24,
                                28,29,30,31,32,33,34,
                                36,37,38,39,40,41,42,43,44};
    float YA[25];
#pragma unroll
    for (int i = 0; i < 25; ++i) YA[i] = Y[lmFlat[i] * G_TOTAL + gc];

    float RA[8];
#pragma unroll
    for (int j = 0; j < 8; ++j) RA[j] = Rb[(kg * 8 + j) * G_TOTAL + gc];

    f32x16 acc0, acc1;
#pragma unroll
    for (int q = 0; q < 16; ++q) { acc0[q] = 0.0f; acc1[q] = 0.0f; }

    __syncthreads();

    // ---- K-loop: 25 steps, A from LDS (ds_read_b128, conflict-free) ----
    const bf16x8* __restrict__ Al = (const bf16x8*)Alds;
#pragma unroll
    for (int ks = 0; ks < 25; ++ks) {
        const float y = YA[ks];
        union { unsigned int u[4]; bf16x8 v; } fb;
#pragma unroll
        for (int p = 0; p < 4; ++p) {
            float lo = y * RA[2 * p];
            float hi = y * RA[2 * p + 1];
            unsigned r;
            asm("v_cvt_pk_bf16_f32 %0, %1, %2" : "=v"(r) : "v"(lo), "v"(hi));
            fb.u[p] = r;   // elem 2p in [15:0], 2p+1 in [31:16] == stage order
        }
        bf16x8 a0 = Al[(ks * 2 + 0) * 64 + l];
        bf16x8 a1 = Al[(ks * 2 + 1) * 64 + l];
        acc0 = __builtin_amdgcn_mfma_f32_32x32x16_bf16(a0, fb.v, acc0, 0, 0, 0);
        acc1 = __builtin_amdgcn_mfma_f32_32x32x16_bf16(a1, fb.v, acc1, 0, 0, 0);
    }

    // ---- epilogue ----
    if (g < G_TOTAL) {
        const int rb0 = (2 * bY)     * 32 + 4 * kg;
        const int rb1 = (2 * bY + 1) * 32 + 4 * kg;
#pragma unroll
        for (int reg = 0; reg < 16; ++reg) {
            int ro = (reg & 3) + 8 * (reg >> 2);
            out[(rb0 + ro) * G_TOTAL + g] = acc0[reg];
            out[(rb1 + ro) * G_TOTAL + g] = acc1[reg];
        }
    }
}

extern "C" void kernel_launch(void* const* d_in, const int* in_sizes, int n_in,
                              void* d_out, int out_size, void* d_ws, size_t ws_size,
                              hipStream_t stream) {
    // pointer identification by element count (robust to dict-order changes)
    const float *pC = nullptr, *pY = nullptr, *pR = nullptr;
    if (n_in >= 3) {
        for (int i = 0; i < 3; ++i) {
            if      (in_sizes[i] == 256 * 720)    pC = (const float*)d_in[i];
            else if (in_sizes[i] == 45 * G_TOTAL) pY = (const float*)d_in[i];
            else if (in_sizes[i] == 16 * G_TOTAL) pR = (const float*)d_in[i];
        }
    }
    if (!pC || !pY || !pR) {
        pC = (const float*)d_in[0];
        pY = (const float*)d_in[1];
        pR = (const float*)d_in[2];
    }

    float* out = (float*)d_out;   // f32 output (r9-verified)

    dim3 grid(141, 4);
    sh_fused<<<grid, 512, 0, stream>>>(pC, pY, pR, out);

    (void)d_ws; (void)ws_size; (void)out_size; (void)n_in;
}